// Round 4
// baseline (588.639 us; speedup 1.0000x reference)
//
#include <hip/hip_runtime.h>

#define S    4096
#define DM   1024
#define H    16
#define DK   64

typedef __bf16 bf16;
typedef __bf16 bf16x8 __attribute__((ext_vector_type(8)));
typedef __bf16 bf16x4 __attribute__((ext_vector_type(4)));
typedef float  f32x4  __attribute__((ext_vector_type(4)));

// ---------------------------------------------------------------------------
// fp32 -> bf16 bulk convert: x (4M elems) + Wq/Wk/Wv/Wo (1M each) = 8M elems.
// ---------------------------------------------------------------------------
__global__ __launch_bounds__(256)
void convert_kernel(const float* __restrict__ x,  const float* __restrict__ wq,
                    const float* __restrict__ wk, const float* __restrict__ wv,
                    const float* __restrict__ wo,
                    bf16* __restrict__ xb,  bf16* __restrict__ wqb,
                    bf16* __restrict__ wkb, bf16* __restrict__ wvb,
                    bf16* __restrict__ wob)
{
    const size_t i = (size_t)blockIdx.x * 256 + threadIdx.x;   // f32x4 index
    const float* src; bf16* dst; size_t off;
    if (i < 1048576)      { src = x;  dst = xb;  off = i; }
    else if (i < 1310720) { src = wq; dst = wqb; off = i - 1048576; }
    else if (i < 1572864) { src = wk; dst = wkb; off = i - 1310720; }
    else if (i < 1835008) { src = wv; dst = wvb; off = i - 1572864; }
    else                  { src = wo; dst = wob; off = i - 1835008; }
    f32x4 v = ((const f32x4*)src)[off];
    bf16x4 b;
    for (int r = 0; r < 4; r++) b[r] = (bf16)v[r];
    ((bf16x4*)dst)[off] = b;
}

// ---------------------------------------------------------------------------
// R4 GEMM: C(4096xDM) = A @ W^T. 128x128 tile, BK=64, 4 waves 2x2, each wave
// a 64x64 output (4x4 16x16x32 frags) -> 2.0 MFMA per ds_read_b128 (R3's 64^2
// structure was 1.0; its LDS-pipe floor ~46us/CU WAS the 68us kernel).
// Staging via global_load_lds width=16 direct to LDS (no reg round-trip, no
// ds_writes). LDS is FRAGMENT-MAJOR: 16 fragments x 1KB, lane-linear, so the
// wave-uniform-dest DMA lands fragments exactly where ds_read_b128 wants them
// (global source address is pre-permuted per lane instead — m173 pattern).
// Every LDS read = 64 consecutive 16B lanes -> bank-conflict-free.
// Global side per DMA instr: 16 rows x 64B aligned sectors (4 quad-lanes
// cover one row's 64B) = perfect sector utilization.
// mode = base_mode + blockIdx.z:
//   0: Q  -> fused RoPE, *0.125*log2(e) (exp2 fold), bf16 [h][s][d]
//   1: K  -> fused RoPE,                             bf16 [h][s][d]
//   2: V  ->                bf16 [h][d][s] (transposed)
//   3: out ->               fp32 [m][n] to d_out
// ---------------------------------------------------------------------------
__global__ __launch_bounds__(256)
void gemm_kernel(const bf16* __restrict__ A,
                 const bf16* __restrict__ w0, const bf16* __restrict__ w1,
                 const bf16* __restrict__ w2,
                 const int* __restrict__ pos,
                 bf16* __restrict__ o0, bf16* __restrict__ o1,
                 bf16* __restrict__ o2,
                 float* __restrict__ of,
                 int base_mode)
{
    const int z    = blockIdx.z;
    const int mode = base_mode + z;
    const bf16* W  = (z == 0) ? w0 : (z == 1 ? w1 : w2);
    bf16* Out      = (z == 0) ? o0 : (z == 1 ? o1 : o2);

    // fragment-major: fragment f = (rg<<1)|kk, rg=row-group of 16, kk=k32.
    // lane l=(quad*16+col) of fragment f holds A[rg*16+col][kk*32+quad*8..+8]
    __shared__ bf16 As[16 * 512];      // 16 KB
    __shared__ bf16 Bs[16 * 512];      // 16 KB

    const int tid  = threadIdx.x;
    const int lane = tid & 63;
    const int wv   = tid >> 6;
    const int quad = lane >> 4;
    const int col  = lane & 15;
    const int wm   = wv >> 1, wn = wv & 1;

    const int tileM = blockIdx.x * 128;
    const int tileN = blockIdx.y * 128;

    f32x4 acc[4][4] = {};

    for (int kc = 0; kc < DM; kc += 64) {
        __syncthreads();               // prior-iter LDS fragment reads done
#pragma unroll
        for (int i = 0; i < 4; i++) {
            const int f  = wv * 4 + i;         // wave stages 4 frags of each
            const int rg = f >> 1, kk = f & 1;
            const size_t go = (size_t)(rg * 16 + col) * DM + kc + kk * 32 + quad * 8;
            __builtin_amdgcn_global_load_lds(
                (const __attribute__((address_space(1))) void*)(A + (size_t)tileM * DM + go),
                (__attribute__((address_space(3))) void*)&As[f * 512], 16, 0, 0);
            __builtin_amdgcn_global_load_lds(
                (const __attribute__((address_space(1))) void*)(W + (size_t)tileN * DM + go),
                (__attribute__((address_space(3))) void*)&Bs[f * 512], 16, 0, 0);
        }
        __syncthreads();               // compiler drains vmcnt(0) before barrier

#pragma unroll
        for (int kk = 0; kk < 2; kk++) {
            bf16x8 af[4], bfr[4];
#pragma unroll
            for (int fm = 0; fm < 4; fm++)
                af[fm] = *(const bf16x8*)&As[(((wm * 4 + fm) << 1) | kk) * 512 + lane * 8];
#pragma unroll
            for (int fn = 0; fn < 4; fn++)
                bfr[fn] = *(const bf16x8*)&Bs[(((wn * 4 + fn) << 1) | kk) * 512 + lane * 8];
#pragma unroll
            for (int fm = 0; fm < 4; fm++)
#pragma unroll
                for (int fn = 0; fn < 4; fn++)
                    acc[fm][fn] = __builtin_amdgcn_mfma_f32_16x16x32_bf16(af[fm], bfr[fn], acc[fm][fn], 0, 0, 0);
        }
    }

    // Epilogue. C/D layout: col = lane&15, row = quad*4 + r  [m89/m91]
    for (int fm = 0; fm < 4; fm++)
    for (int fn = 0; fn < 4; fn++) {
        f32x4 v = acc[fm][fn];
        const int n = tileN + wn * 64 + fn * 16 + col;
        for (int r = 0; r < 4; r++) {
            const int m = tileM + wm * 64 + fm * 16 + quad * 4 + r;
            float val = v[r];
            if (mode <= 1) {
                // RoPE: pairs (2i,2i+1); partner value lives in lane^1
                float part = __shfl_xor(val, 1);
                const int d = n & 63;
                const int i = d >> 1;
                float inv = exp2f(-(float)i * 0.41524101186092034f); // 1e4^(-i/32)
                float ang = (float)pos[m] * inv;
                float c = cosf(ang), sn = sinf(ang);
                float rot = (n & 1) ? (val * c + part * sn)
                                    : (val * c - part * sn);
                // Q: fold 1/sqrt(DK) AND log2(e) so attn can use raw exp2
                if (mode == 0) rot *= 0.18033688011112042f;   // 0.125*log2(e)
                Out[((size_t)(n >> 6) * S + m) * 64 + d] = (bf16)rot;
            } else if (mode == 2) {
                Out[(size_t)n * S + m] = (bf16)val;           // V^T [h][d][s]
            } else {
                of[(size_t)m * DM + n] = val;                 // d_out fp32
            }
        }
    }
}

// ---------------------------------------------------------------------------
// Flash attention (causal), transposed scores: St = K.Q^T, col = query.
// UNSHIFTED softmax -> partial (o,l) over disjoint key ranges sum linearly.
// R3: 64 QUERIES PER WAVE (block = 4 waves x 64 q = 256 q); K/V LDS reads
// amortized 4x vs R1. Split-K=2, antithetic pairing, XCD head-pinning.
// (Verified R3: attn dropped below the 68us top-5 cutoff, was 122us.)
// ---------------------------------------------------------------------------
__global__ __launch_bounds__(256, 2)
void attn_kernel(const bf16* __restrict__ q, const bf16* __restrict__ k,
                 const bf16* __restrict__ vt,
                 bf16* __restrict__ P0g, bf16* __restrict__ P1g,
                 float* __restrict__ l0g, float* __restrict__ l1g)
{
    const int bid = blockIdx.x;
    const int xcd = bid & 7;
    const int b3  = (bid >> 3) & 1;
    const int u   = (bid >> 4) & 15;
    const int b8  = (bid >> 8) & 1;
    const int h   = (xcd << 1) | b8;
    const int z   = b3;
    const int QB  = (b3 == b8) ? (15 - u) : u;   // antithetic pair balance

    const int tid  = threadIdx.x;
    const int lane = tid & 63;
    const int wv   = tid >> 6;
    const int quad = lane >> 4;
    const int col  = lane & 15;

    const int T2  = 2 * QB + 2;          // tiles per split-K chunk
    const int kt0 = z * T2;
    const int kt1 = kt0 + T2;

    __shared__ bf16 Ks[64 * 72];         // K[key][d],   padded (2-way free)
    __shared__ bf16 Vs[64 * 72];         // V^T[d][key], padded
    __shared__ bf16 plds[4][64 * 40];    // per-wave P half-tile [q][32key+pad]

    const int qbase = QB * 256 + wv * 64;    // wave owns 64 queries

    // Q as B-operand fragments: B[n=q][kdim=d], 4 q-groups of 16
    bf16x8 qf[4][2];
#pragma unroll
    for (int qt = 0; qt < 4; qt++) {
        const bf16* qr = &q[((size_t)(h * S + qbase + qt * 16 + col)) * 64];
        qf[qt][0] = *(const bf16x8*)(qr + quad * 8);
        qf[qt][1] = *(const bf16x8*)(qr + 32 + quad * 8);
    }

    float li[4] = {};
    f32x4 o[4][4] = {};                  // [dg][qt]

    const int srow = tid >> 2;
    const int sseg = (tid & 3) * 16;
    const bf16* kg_ = k  + ((size_t)h * S) * 64;
    const bf16* vg_ = vt + ((size_t)h * 64) * S;

    // preload first tile of this chunk
    bf16x8 kr0 = *(const bf16x8*)(kg_ + (size_t)(kt0 * 64 + srow) * 64 + sseg);
    bf16x8 kr1 = *(const bf16x8*)(kg_ + (size_t)(kt0 * 64 + srow) * 64 + sseg + 8);
    bf16x8 vr0 = *(const bf16x8*)(vg_ + (size_t)srow * S + kt0 * 64 + sseg);
    bf16x8 vr1 = *(const bf16x8*)(vg_ + (size_t)srow * S + kt0 * 64 + sseg + 8);

    for (int kt = kt0; kt < kt1; kt++) {
        const int kbase = kt * 64;

        __syncthreads();                 // prior-iter LDS fragment reads done
        *(bf16x8*)&Ks[srow * 72 + sseg]     = kr0;
        *(bf16x8*)&Ks[srow * 72 + sseg + 8] = kr1;
        *(bf16x8*)&Vs[srow * 72 + sseg]     = vr0;
        *(bf16x8*)&Vs[srow * 72 + sseg + 8] = vr1;
        __syncthreads();

        // register-prefetch next tile (overlaps with compute below)
        if (kt + 1 < kt1) {
            const int nb = kbase + 64;
            kr0 = *(const bf16x8*)(kg_ + (size_t)(nb + srow) * 64 + sseg);
            kr1 = *(const bf16x8*)(kg_ + (size_t)(nb + srow) * 64 + sseg + 8);
            vr0 = *(const bf16x8*)(vg_ + (size_t)srow * S + nb + sseg);
            vr1 = *(const bf16x8*)(vg_ + (size_t)srow * S + nb + sseg + 8);
        }

        const bool diag = (kt >= (QB << 2));   // tile overlaps causal diagonal

        // Process 64 keys in two 32-key halves (plds holds one half)
#pragma unroll
        for (int half = 0; half < 2; half++) {
            __builtin_amdgcn_wave_barrier();   // prior half's P reads done
#pragma unroll
            for (int kg2 = 0; kg2 < 2; kg2++) {
                const int kg = half * 2 + kg2;
                // K A-fragments (shared across the 4 q-groups)
                bf16x8 kf0 = *(const bf16x8*)&Ks[(kg * 16 + col) * 72 + quad * 8];
                bf16x8 kf1 = *(const bf16x8*)&Ks[(kg * 16 + col) * 72 + 32 + quad * 8];

                f32x4 st[4];
                __builtin_amdgcn_s_setprio(1);
#pragma unroll
                for (int qt = 0; qt < 4; qt++) {
                    f32x4 zz = {};
                    zz = __builtin_amdgcn_mfma_f32_16x16x32_bf16(kf0, qf[qt][0], zz, 0, 0, 0);
                    zz = __builtin_amdgcn_mfma_f32_16x16x32_bf16(kf1, qf[qt][1], zz, 0, 0, 0);
                    st[qt] = zz;
                }
                __builtin_amdgcn_s_setprio(0);

                if (diag) {
#pragma unroll
                    for (int qt = 0; qt < 4; qt++) {
                        const int gq = qbase + qt * 16 + col;
#pragma unroll
                        for (int r = 0; r < 4; r++) {
                            const int gk = kbase + kg * 16 + quad * 4 + r;
                            st[qt][r] = (gk > gq) ? -1e30f : st[qt][r];
                        }
                    }
                }

                // p = exp2(s) raw; accumulate per-lane partial l (reduce once
                // at the end); write P half-tile (b64, packed)
#pragma unroll
                for (int qt = 0; qt < 4; qt++) {
                    bf16x4 pk;
#pragma unroll
                    for (int r = 0; r < 4; r++) {
                        float p;
                        asm("v_exp_f32 %0, %1" : "=v"(p) : "v"(st[qt][r]));
                        li[qt] += p;
                        pk[r] = (bf16)p;
                    }
                    *(bf16x4*)&plds[wv][(qt * 16 + col) * 40 + kg2 * 16 + quad * 4] = pk;
                }
            }

            __builtin_amdgcn_wave_barrier();   // P writes before P reads

            // PV for this 32-key half: O^T[d][q] += V^T[d][key] * P^T[key][q]
            bf16x8 pb[4];
#pragma unroll
            for (int qt = 0; qt < 4; qt++)
                pb[qt] = *(const bf16x8*)&plds[wv][(qt * 16 + col) * 40 + quad * 8];

            __builtin_amdgcn_s_setprio(1);
#pragma unroll
            for (int dg = 0; dg < 4; dg++) {
                bf16x8 va = *(const bf16x8*)&Vs[(dg * 16 + col) * 72 + half * 32 + quad * 8];
#pragma unroll
                for (int qt = 0; qt < 4; qt++)
                    o[dg][qt] = __builtin_amdgcn_mfma_f32_16x16x32_bf16(va, pb[qt], o[dg][qt], 0, 0, 0);
            }
            __builtin_amdgcn_s_setprio(0);
        }
    }

    // Cross-quad l reduction (keys split across quads), once per kernel
#pragma unroll
    for (int qt = 0; qt < 4; qt++) {
        li[qt] += __shfl_xor(li[qt], 16);
        li[qt] += __shfl_xor(li[qt], 32);
    }

    // Epilogue: store UNNORMALIZED partial o (bf16) + partial l (fp32).
    bf16*  Pz = z ? P1g : P0g;
    float* lz = z ? l1g : l0g;
#pragma unroll
    for (int dg = 0; dg < 4; dg++)
#pragma unroll
    for (int qt = 0; qt < 4; qt++) {
        const int gq = qbase + qt * 16 + col;
        bf16x4 ov;
#pragma unroll
        for (int r = 0; r < 4; r++) ov[r] = (bf16)o[dg][qt][r];
        *(bf16x4*)&Pz[(size_t)gq * DM + h * 64 + dg * 16 + quad * 4] = ov;
    }
    if (quad == 0) {
#pragma unroll
        for (int qt = 0; qt < 4; qt++)
            lz[(size_t)h * S + qbase + qt * 16 + col] = li[qt];
    }
}

// ---------------------------------------------------------------------------
// Combine split-K partials: ao[s][dm] = (P0 + P1) / (l0[h][s] + l1[h][s]).
// ---------------------------------------------------------------------------
__global__ __launch_bounds__(256)
void combine_kernel(const bf16* __restrict__ P0, const bf16* __restrict__ P1,
                    const float* __restrict__ l0, const float* __restrict__ l1,
                    bf16* __restrict__ ao)
{
    const size_t i    = (size_t)blockIdx.x * 256 + threadIdx.x;  // 8-elem group
    const size_t base = i * 8;
    const int s  = (int)(base >> 10);          // DM = 1024
    const int dm = (int)(base & 1023);
    const int h  = dm >> 6;
    const float rli = 1.f / (l0[(size_t)h * S + s] + l1[(size_t)h * S + s]);
    bf16x8 a = *(const bf16x8*)&P0[base];
    bf16x8 b = *(const bf16x8*)&P1[base];
    bf16x8 ov;
    for (int r = 0; r < 8; r++)
        ov[r] = (bf16)(((float)a[r] + (float)b[r]) * rli);
    *(bf16x8*)&ao[base] = ov;
}

// ---------------------------------------------------------------------------
extern "C" void kernel_launch(void* const* d_in, const int* in_sizes, int n_in,
                              void* d_out, int out_size, void* d_ws, size_t ws_size,
                              hipStream_t stream)
{
    const float* x   = (const float*)d_in[0];
    const int*   pos = (const int*)d_in[1];
    const float* Wq  = (const float*)d_in[2];
    const float* Wk  = (const float*)d_in[3];
    const float* Wv  = (const float*)d_in[4];
    const float* Wo  = (const float*)d_in[5];
    float* out = (float*)d_out;   // reference output dtype is float32

    // workspace layout (48 MB), regions recycled across phases:
    //   [0, 8M)    xb  bf16 [s][DM]        -> P0 bf16 partial (after QKV gemm)
    //   [8,16M)    wqb/wkb/wvb             -> P1 bf16 partial (after QKV gemm)
    //   [16,24M)   qb  bf16 [h][s][d]      -> ao bf16 [s][DM] (after attn)
    //   [24,32M)   kb  bf16 [h][s][d]
    //   [32,40M)   vt  bf16 [h][d][s]
    //   [40,40.25M) l0 fp32 [h][s]   [40.25,40.5M) l1 fp32 [h][s]
    //   [46,48M)   wob bf16
    char* w = (char*)d_ws;
    bf16*  xb  = (bf16*)(w);
    bf16*  wqb = (bf16*)(w + (size_t) 8 * 1024 * 1024);
    bf16*  wkb = (bf16*)(w + (size_t)10 * 1024 * 1024);
    bf16*  wvb = (bf16*)(w + (size_t)12 * 1024 * 1024);
    bf16*  P0  = (bf16*)(w);
    bf16*  P1  = (bf16*)(w + (size_t) 8 * 1024 * 1024);
    bf16*  qb  = (bf16*)(w + (size_t)16 * 1024 * 1024);
    bf16*  kb  = (bf16*)(w + (size_t)24 * 1024 * 1024);
    bf16*  vt  = (bf16*)(w + (size_t)32 * 1024 * 1024);
    float* l0  = (float*)(w + (size_t)40 * 1024 * 1024);
    float* l1  = (float*)(w + (size_t)40 * 1024 * 1024 + 256 * 1024);
    bf16*  ao  = (bf16*)(w + (size_t)16 * 1024 * 1024);   // alias qb (dead)
    bf16*  wob = (bf16*)(w + (size_t)46 * 1024 * 1024);

    dim3 blk(256);
    convert_kernel<<<dim3(8192), blk, 0, stream>>>(x, Wq, Wk, Wv, Wo,
                                                   xb, wqb, wkb, wvb, wob);
    gemm_kernel<<<dim3(32, 8, 3), blk, 0, stream>>>(xb, wqb, wkb, wvb, pos,
                                                    qb, kb, vt, out, 0);
    attn_kernel<<<dim3(512), blk, 0, stream>>>(qb, kb, vt,
                                               P0, P1, l0, l1);
    combine_kernel<<<dim3(2048), blk, 0, stream>>>(P0, P1, l0, l1, ao);
    gemm_kernel<<<dim3(32, 8, 1), blk, 0, stream>>>(ao, wob, wob, wob, pos,
                                                    P0, P0, P0, out, 3);
}

// Round 5
// 476.614 us; speedup vs baseline: 1.2350x; 1.2350x over previous
//
#include <hip/hip_runtime.h>

#define S    4096
#define DM   1024
#define H    16
#define DK   64

typedef __bf16 bf16;
typedef __bf16 bf16x8 __attribute__((ext_vector_type(8)));
typedef __bf16 bf16x4 __attribute__((ext_vector_type(4)));
typedef float  f32x4  __attribute__((ext_vector_type(4)));

// ---------------------------------------------------------------------------
// fp32 -> bf16 bulk convert: x (4M elems) + Wq/Wk/Wv/Wo (1M each) = 8M elems.
// ---------------------------------------------------------------------------
__global__ __launch_bounds__(256)
void convert_kernel(const float* __restrict__ x,  const float* __restrict__ wq,
                    const float* __restrict__ wk, const float* __restrict__ wv,
                    const float* __restrict__ wo,
                    bf16* __restrict__ xb,  bf16* __restrict__ wqb,
                    bf16* __restrict__ wkb, bf16* __restrict__ wvb,
                    bf16* __restrict__ wob)
{
    const size_t i = (size_t)blockIdx.x * 256 + threadIdx.x;   // f32x4 index
    const float* src; bf16* dst; size_t off;
    if (i < 1048576)      { src = x;  dst = xb;  off = i; }
    else if (i < 1310720) { src = wq; dst = wqb; off = i - 1048576; }
    else if (i < 1572864) { src = wk; dst = wkb; off = i - 1310720; }
    else if (i < 1835008) { src = wv; dst = wvb; off = i - 1572864; }
    else                  { src = wo; dst = wob; off = i - 1835008; }
    f32x4 v = ((const f32x4*)src)[off];
    bf16x4 b;
    for (int r = 0; r < 4; r++) b[r] = (bf16)v[r];
    ((bf16x4*)dst)[off] = b;
}

// ---------------------------------------------------------------------------
// R5 QKV GEMM: C(4096x1024) = x @ W^T for W in {Wq,Wk,Wv}. 128x128 tile,
// BK=64, 4 waves 2x2, wave = 64x64 (4x4 frags) -> 2 MFMA per ds_read_b128.
// Main loop = R4's verified structure (global_load_lds width-16 into
// FRAGMENT-MAJOR LDS; R4 counters: SQ_LDS_BANK_CONFLICT == 0).
// R4's failure was the EPILOGUE: per-element 2B scatter stores at 128^2
// geometry defeated sector merging -> WRITE_SIZE 1.17 GB (45x payload),
// 3.9 TB/s of write-storm + L2/L3 thrash (FETCH 4x). Third independent
// measurement of this failure mode on this op.
// Fix: LDS-staged epilogue. RoPE in-register (unchanged), stage bf16 result
// into Cs[128][136] (reuses As/Bs space after barrier; stride 136 = 272B
// rows -> staging writes <=2-way bank-aliased = free; 16B-aligned rows),
// m-major for Q/K, n-major (transposed) for V^T. Then 256 threads stream
// Cs out as bf16x8 stores in 128-256B contiguous runs: sector-complete for
// all three output layouts.
//   z=0: Q -> RoPE, *0.125*log2(e), bf16 [h][s][d]
//   z=1: K -> RoPE,                 bf16 [h][s][d]
//   z=2: V ->                       bf16 [h][d][s]
// ---------------------------------------------------------------------------
__global__ __launch_bounds__(256)
void gemm128_kernel(const bf16* __restrict__ A,
                    const bf16* __restrict__ w0, const bf16* __restrict__ w1,
                    const bf16* __restrict__ w2,
                    const int* __restrict__ pos,
                    bf16* __restrict__ o0, bf16* __restrict__ o1,
                    bf16* __restrict__ o2)
{
    const int mode = blockIdx.z;
    const bf16* W  = (mode == 0) ? w0 : (mode == 1 ? w1 : w2);
    bf16* Out      = (mode == 0) ? o0 : (mode == 1 ? o1 : o2);

    // union: main loop uses As[0,8192) Bs[8192,16384); epilogue reuses the
    // whole region as Cs[128][136] (17408 elems) after a barrier.
    __shared__ bf16 smem[17408];
    bf16* As = smem;
    bf16* Bs = smem + 8192;
    bf16* Cs = smem;

    const int tid  = threadIdx.x;
    const int lane = tid & 63;
    const int wv   = tid >> 6;
    const int quad = lane >> 4;
    const int col  = lane & 15;
    const int wm   = wv >> 1, wn = wv & 1;

    const int tileM = blockIdx.x * 128;
    const int tileN = blockIdx.y * 128;

    f32x4 acc[4][4] = {};

    for (int kc = 0; kc < DM; kc += 64) {
        __syncthreads();               // prior-iter LDS fragment reads done
#pragma unroll
        for (int i = 0; i < 4; i++) {
            const int f  = wv * 4 + i;         // wave stages 4 frags of each
            const int rg = f >> 1, kk = f & 1;
            const size_t go = (size_t)(rg * 16 + col) * DM + kc + kk * 32 + quad * 8;
            __builtin_amdgcn_global_load_lds(
                (const __attribute__((address_space(1))) void*)(A + (size_t)tileM * DM + go),
                (__attribute__((address_space(3))) void*)&As[f * 512], 16, 0, 0);
            __builtin_amdgcn_global_load_lds(
                (const __attribute__((address_space(1))) void*)(W + (size_t)tileN * DM + go),
                (__attribute__((address_space(3))) void*)&Bs[f * 512], 16, 0, 0);
        }
        __syncthreads();               // vmcnt(0) drained before barrier

#pragma unroll
        for (int kk = 0; kk < 2; kk++) {
            bf16x8 af[4], bfr[4];
#pragma unroll
            for (int fm = 0; fm < 4; fm++)
                af[fm] = *(const bf16x8*)&As[(((wm * 4 + fm) << 1) | kk) * 512 + lane * 8];
#pragma unroll
            for (int fn = 0; fn < 4; fn++)
                bfr[fn] = *(const bf16x8*)&Bs[(((wn * 4 + fn) << 1) | kk) * 512 + lane * 8];
#pragma unroll
            for (int fm = 0; fm < 4; fm++)
#pragma unroll
                for (int fn = 0; fn < 4; fn++)
                    acc[fm][fn] = __builtin_amdgcn_mfma_f32_16x16x32_bf16(af[fm], bfr[fn], acc[fm][fn], 0, 0, 0);
        }
    }

    __syncthreads();   // all waves' last MFMA LDS reads done; Cs may overwrite

    // ---- stage into Cs ----  C/D layout: col = lane&15, row = quad*4+r
    if (mode <= 1) {
        // Q/K: RoPE per-lane, then Cs[m][nl] (m-major), scalar b16 writes.
#pragma unroll
        for (int fm = 0; fm < 4; fm++)
#pragma unroll
        for (int fn = 0; fn < 4; fn++) {
            f32x4 v = acc[fm][fn];
            const int nl = wn * 64 + fn * 16 + col;   // tile-local n, 0..127
            const int d  = nl & 63;
            const int ii = d >> 1;
            const float inv = exp2f(-(float)ii * 0.41524101186092034f); // 1e4^(-i/32)
#pragma unroll
            for (int r = 0; r < 4; r++) {
                const int m  = wm * 64 + fm * 16 + quad * 4 + r;   // tile-local
                float val  = v[r];
                float part = __shfl_xor(val, 1);      // partner nl^1, same r
                float ang  = (float)pos[tileM + m] * inv;
                float c = cosf(ang), sn = sinf(ang);
                float rot = (nl & 1) ? (val * c + part * sn)
                                     : (val * c - part * sn);
                if (mode == 0) rot *= 0.18033688011112042f;   // 0.125*log2(e)
                Cs[m * 136 + nl] = (bf16)rot;
            }
        }
    } else {
        // V^T: Cs[nl][m] (n-major), b64 writes (4 consecutive m per lane).
#pragma unroll
        for (int fm = 0; fm < 4; fm++)
#pragma unroll
        for (int fn = 0; fn < 4; fn++) {
            const int nl    = wn * 64 + fn * 16 + col;
            const int mbase = wm * 64 + fm * 16 + quad * 4;
            bf16x4 pk;
#pragma unroll
            for (int r = 0; r < 4; r++) pk[r] = (bf16)acc[fm][fn][r];
            *(bf16x4*)&Cs[nl * 136 + mbase] = pk;
        }
    }
    __syncthreads();

    // ---- coalesced readout: 2048 bf16x8 chunks, 16 chunks per Cs row ----
#pragma unroll
    for (int i = 0; i < 8; i++) {
        const int c   = i * 256 + tid;
        const int row = c >> 4;             // Cs row (m for Q/K, nl for V^T)
        const int off = (c & 15) * 8;       // elem offset within row, 0..120
        bf16x8 vv = *(const bf16x8*)&Cs[row * 136 + off];
        if (mode <= 1) {
            // Q/K [h][s][d]: head = by*2 + (off>>6), d = off&63
            const int head = blockIdx.y * 2 + (off >> 6);
            *(bf16x8*)&Out[((size_t)head * S + tileM + row) * 64 + (off & 63)] = vv;
        } else {
            // V^T [h][d][s]: column = tileN+row, keys tileM+off..+7
            *(bf16x8*)&Out[(size_t)(tileN + row) * S + tileM + off] = vv;
        }
    }
}

// ---------------------------------------------------------------------------
// R3-proven 64^2 GEMM, used for the OUT-PROJECTION only (mode 3, fp32 out,
// coalesced 64B stores, grid (64,16) = 4 blocks/CU). Measured ~23us in R3.
// ---------------------------------------------------------------------------
__global__ __launch_bounds__(256)
void gemm64_kernel(const bf16* __restrict__ A,
                   const bf16* __restrict__ W,
                   float* __restrict__ of)
{
    __shared__ bf16 As[64 * 72];
    __shared__ bf16 Bs[64 * 72];

    const int tid  = threadIdx.x;
    const int lane = tid & 63;
    const int wv   = tid >> 6;
    const int quad = lane >> 4;
    const int col  = lane & 15;
    const int wm   = wv >> 1, wn = wv & 1;

    const int tileM = blockIdx.x * 64;
    const int tileN = blockIdx.y * 64;

    const int ldRow = tid >> 2;         // 0..63
    const int ldK   = (tid & 3) * 16;   // 0,16,32,48 (elements)

    f32x4 acc[2][2] = {};

    for (int kc = 0; kc < DM; kc += 64) {
        bf16x8 a0 = *(const bf16x8*)&A[(size_t)(tileM + ldRow) * DM + kc + ldK];
        bf16x8 a1 = *(const bf16x8*)&A[(size_t)(tileM + ldRow) * DM + kc + ldK + 8];
        bf16x8 b0 = *(const bf16x8*)&W[(size_t)(tileN + ldRow) * DM + kc + ldK];
        bf16x8 b1 = *(const bf16x8*)&W[(size_t)(tileN + ldRow) * DM + kc + ldK + 8];
        __syncthreads();                       // prior-iter LDS reads done
        *(bf16x8*)&As[ldRow * 72 + ldK]     = a0;
        *(bf16x8*)&As[ldRow * 72 + ldK + 8] = a1;
        *(bf16x8*)&Bs[ldRow * 72 + ldK]     = b0;
        *(bf16x8*)&Bs[ldRow * 72 + ldK + 8] = b1;
        __syncthreads();

        for (int kk = 0; kk < 2; kk++) {
            bf16x8 af0 = *(const bf16x8*)&As[(wm * 32 + 0 * 16 + col) * 72 + kk * 32 + quad * 8];
            bf16x8 af1 = *(const bf16x8*)&As[(wm * 32 + 1 * 16 + col) * 72 + kk * 32 + quad * 8];
            bf16x8 bf0 = *(const bf16x8*)&Bs[(wn * 32 + 0 * 16 + col) * 72 + kk * 32 + quad * 8];
            bf16x8 bf1 = *(const bf16x8*)&Bs[(wn * 32 + 1 * 16 + col) * 72 + kk * 32 + quad * 8];

            acc[0][0] = __builtin_amdgcn_mfma_f32_16x16x32_bf16(af0, bf0, acc[0][0], 0, 0, 0);
            acc[0][1] = __builtin_amdgcn_mfma_f32_16x16x32_bf16(af0, bf1, acc[0][1], 0, 0, 0);
            acc[1][0] = __builtin_amdgcn_mfma_f32_16x16x32_bf16(af1, bf0, acc[1][0], 0, 0, 0);
            acc[1][1] = __builtin_amdgcn_mfma_f32_16x16x32_bf16(af1, bf1, acc[1][1], 0, 0, 0);
        }
    }

    // Epilogue: fp32 direct, n-consecutive lanes -> 64B sectors (R3-proven)
    for (int fm = 0; fm < 2; fm++)
    for (int fn = 0; fn < 2; fn++) {
        f32x4 v = acc[fm][fn];
        const int n = tileN + wn * 32 + fn * 16 + col;
        for (int r = 0; r < 4; r++) {
            const int m = tileM + wm * 32 + fm * 16 + quad * 4 + r;
            of[(size_t)m * DM + n] = v[r];
        }
    }
}

// ---------------------------------------------------------------------------
// Flash attention (causal), transposed scores: St = K.Q^T, col = query.
// UNSHIFTED softmax -> partial (o,l) over disjoint key ranges sum linearly.
// R3 structure (verified): 64 queries/wave, split-K=2, antithetic pairing,
// XCD head-pinning. Attn fell below the top-5 cutoff in R3/R4 (~60us).
// ---------------------------------------------------------------------------
__global__ __launch_bounds__(256, 2)
void attn_kernel(const bf16* __restrict__ q, const bf16* __restrict__ k,
                 const bf16* __restrict__ vt,
                 bf16* __restrict__ P0g, bf16* __restrict__ P1g,
                 float* __restrict__ l0g, float* __restrict__ l1g)
{
    const int bid = blockIdx.x;
    const int xcd = bid & 7;
    const int b3  = (bid >> 3) & 1;
    const int u   = (bid >> 4) & 15;
    const int b8  = (bid >> 8) & 1;
    const int h   = (xcd << 1) | b8;
    const int z   = b3;
    const int QB  = (b3 == b8) ? (15 - u) : u;   // antithetic pair balance

    const int tid  = threadIdx.x;
    const int lane = tid & 63;
    const int wv   = tid >> 6;
    const int quad = lane >> 4;
    const int col  = lane & 15;

    const int T2  = 2 * QB + 2;          // tiles per split-K chunk
    const int kt0 = z * T2;
    const int kt1 = kt0 + T2;

    __shared__ bf16 Ks[64 * 72];         // K[key][d],   padded (2-way free)
    __shared__ bf16 Vs[64 * 72];         // V^T[d][key], padded
    __shared__ bf16 plds[4][64 * 40];    // per-wave P half-tile [q][32key+pad]

    const int qbase = QB * 256 + wv * 64;    // wave owns 64 queries

    // Q as B-operand fragments: B[n=q][kdim=d], 4 q-groups of 16
    bf16x8 qf[4][2];
#pragma unroll
    for (int qt = 0; qt < 4; qt++) {
        const bf16* qr = &q[((size_t)(h * S + qbase + qt * 16 + col)) * 64];
        qf[qt][0] = *(const bf16x8*)(qr + quad * 8);
        qf[qt][1] = *(const bf16x8*)(qr + 32 + quad * 8);
    }

    float li[4] = {};
    f32x4 o[4][4] = {};                  // [dg][qt]

    const int srow = tid >> 2;
    const int sseg = (tid & 3) * 16;
    const bf16* kg_ = k  + ((size_t)h * S) * 64;
    const bf16* vg_ = vt + ((size_t)h * 64) * S;

    // preload first tile of this chunk
    bf16x8 kr0 = *(const bf16x8*)(kg_ + (size_t)(kt0 * 64 + srow) * 64 + sseg);
    bf16x8 kr1 = *(const bf16x8*)(kg_ + (size_t)(kt0 * 64 + srow) * 64 + sseg + 8);
    bf16x8 vr0 = *(const bf16x8*)(vg_ + (size_t)srow * S + kt0 * 64 + sseg);
    bf16x8 vr1 = *(const bf16x8*)(vg_ + (size_t)srow * S + kt0 * 64 + sseg + 8);

    for (int kt = kt0; kt < kt1; kt++) {
        const int kbase = kt * 64;

        __syncthreads();                 // prior-iter LDS fragment reads done
        *(bf16x8*)&Ks[srow * 72 + sseg]     = kr0;
        *(bf16x8*)&Ks[srow * 72 + sseg + 8] = kr1;
        *(bf16x8*)&Vs[srow * 72 + sseg]     = vr0;
        *(bf16x8*)&Vs[srow * 72 + sseg + 8] = vr1;
        __syncthreads();

        // register-prefetch next tile (overlaps with compute below)
        if (kt + 1 < kt1) {
            const int nb = kbase + 64;
            kr0 = *(const bf16x8*)(kg_ + (size_t)(nb + srow) * 64 + sseg);
            kr1 = *(const bf16x8*)(kg_ + (size_t)(nb + srow) * 64 + sseg + 8);
            vr0 = *(const bf16x8*)(vg_ + (size_t)srow * S + nb + sseg);
            vr1 = *(const bf16x8*)(vg_ + (size_t)srow * S + nb + sseg + 8);
        }

        const bool diag = (kt >= (QB << 2));   // tile overlaps causal diagonal

        // Process 64 keys in two 32-key halves (plds holds one half)
#pragma unroll
        for (int half = 0; half < 2; half++) {
            __builtin_amdgcn_wave_barrier();   // prior half's P reads done
#pragma unroll
            for (int kg2 = 0; kg2 < 2; kg2++) {
                const int kg = half * 2 + kg2;
                // K A-fragments (shared across the 4 q-groups)
                bf16x8 kf0 = *(const bf16x8*)&Ks[(kg * 16 + col) * 72 + quad * 8];
                bf16x8 kf1 = *(const bf16x8*)&Ks[(kg * 16 + col) * 72 + 32 + quad * 8];

                f32x4 st[4];
                __builtin_amdgcn_s_setprio(1);
#pragma unroll
                for (int qt = 0; qt < 4; qt++) {
                    f32x4 zz = {};
                    zz = __builtin_amdgcn_mfma_f32_16x16x32_bf16(kf0, qf[qt][0], zz, 0, 0, 0);
                    zz = __builtin_amdgcn_mfma_f32_16x16x32_bf16(kf1, qf[qt][1], zz, 0, 0, 0);
                    st[qt] = zz;
                }
                __builtin_amdgcn_s_setprio(0);

                if (diag) {
#pragma unroll
                    for (int qt = 0; qt < 4; qt++) {
                        const int gq = qbase + qt * 16 + col;
#pragma unroll
                        for (int r = 0; r < 4; r++) {
                            const int gk = kbase + kg * 16 + quad * 4 + r;
                            st[qt][r] = (gk > gq) ? -1e30f : st[qt][r];
                        }
                    }
                }

                // p = exp2(s) raw; accumulate per-lane partial l (reduce once
                // at the end); write P half-tile (b64, packed)
#pragma unroll
                for (int qt = 0; qt < 4; qt++) {
                    bf16x4 pk;
#pragma unroll
                    for (int r = 0; r < 4; r++) {
                        float p;
                        asm("v_exp_f32 %0, %1" : "=v"(p) : "v"(st[qt][r]));
                        li[qt] += p;
                        pk[r] = (bf16)p;
                    }
                    *(bf16x4*)&plds[wv][(qt * 16 + col) * 40 + kg2 * 16 + quad * 4] = pk;
                }
            }

            __builtin_amdgcn_wave_barrier();   // P writes before P reads

            // PV for this 32-key half: O^T[d][q] += V^T[d][key] * P^T[key][q]
            bf16x8 pb[4];
#pragma unroll
            for (int qt = 0; qt < 4; qt++)
                pb[qt] = *(const bf16x8*)&plds[wv][(qt * 16 + col) * 40 + quad * 8];

            __builtin_amdgcn_s_setprio(1);
#pragma unroll
            for (int dg = 0; dg < 4; dg++) {
                bf16x8 va = *(const bf16x8*)&Vs[(dg * 16 + col) * 72 + half * 32 + quad * 8];
#pragma unroll
                for (int qt = 0; qt < 4; qt++)
                    o[dg][qt] = __builtin_amdgcn_mfma_f32_16x16x32_bf16(va, pb[qt], o[dg][qt], 0, 0, 0);
            }
            __builtin_amdgcn_s_setprio(0);
        }
    }

    // Cross-quad l reduction (keys split across quads), once per kernel
#pragma unroll
    for (int qt = 0; qt < 4; qt++) {
        li[qt] += __shfl_xor(li[qt], 16);
        li[qt] += __shfl_xor(li[qt], 32);
    }

    // Epilogue: store UNNORMALIZED partial o (bf16) + partial l (fp32).
    bf16*  Pz = z ? P1g : P0g;
    float* lz = z ? l1g : l0g;
#pragma unroll
    for (int dg = 0; dg < 4; dg++)
#pragma unroll
    for (int qt = 0; qt < 4; qt++) {
        const int gq = qbase + qt * 16 + col;
        bf16x4 ov;
#pragma unroll
        for (int r = 0; r < 4; r++) ov[r] = (bf16)o[dg][qt][r];
        *(bf16x4*)&Pz[(size_t)gq * DM + h * 64 + dg * 16 + quad * 4] = ov;
    }
    if (quad == 0) {
#pragma unroll
        for (int qt = 0; qt < 4; qt++)
            lz[(size_t)h * S + qbase + qt * 16 + col] = li[qt];
    }
}

// ---------------------------------------------------------------------------
// Combine split-K partials: ao[s][dm] = (P0 + P1) / (l0[h][s] + l1[h][s]).
// ---------------------------------------------------------------------------
__global__ __launch_bounds__(256)
void combine_kernel(const bf16* __restrict__ P0, const bf16* __restrict__ P1,
                    const float* __restrict__ l0, const float* __restrict__ l1,
                    bf16* __restrict__ ao)
{
    const size_t i    = (size_t)blockIdx.x * 256 + threadIdx.x;  // 8-elem group
    const size_t base = i * 8;
    const int s  = (int)(base >> 10);          // DM = 1024
    const int dm = (int)(base & 1023);
    const int h  = dm >> 6;
    const float rli = 1.f / (l0[(size_t)h * S + s] + l1[(size_t)h * S + s]);
    bf16x8 a = *(const bf16x8*)&P0[base];
    bf16x8 b = *(const bf16x8*)&P1[base];
    bf16x8 ov;
    for (int r = 0; r < 8; r++)
        ov[r] = (bf16)(((float)a[r] + (float)b[r]) * rli);
    *(bf16x8*)&ao[base] = ov;
}

// ---------------------------------------------------------------------------
extern "C" void kernel_launch(void* const* d_in, const int* in_sizes, int n_in,
                              void* d_out, int out_size, void* d_ws, size_t ws_size,
                              hipStream_t stream)
{
    const float* x   = (const float*)d_in[0];
    const int*   pos = (const int*)d_in[1];
    const float* Wq  = (const float*)d_in[2];
    const float* Wk  = (const float*)d_in[3];
    const float* Wv  = (const float*)d_in[4];
    const float* Wo  = (const float*)d_in[5];
    float* out = (float*)d_out;   // reference output dtype is float32

    // workspace layout (48 MB), regions recycled across phases:
    //   [0, 8M)    xb  bf16 [s][DM]        -> P0 bf16 partial (after QKV gemm)
    //   [8,16M)    wqb/wkb/wvb             -> P1 bf16 partial (after QKV gemm)
    //   [16,24M)   qb  bf16 [h][s][d]      -> ao bf16 [s][DM] (after attn)
    //   [24,32M)   kb  bf16 [h][s][d]
    //   [32,40M)   vt  bf16 [h][d][s]
    //   [40,40.25M) l0 fp32 [h][s]   [40.25,40.5M) l1 fp32 [h][s]
    //   [46,48M)   wob bf16
    char* w = (char*)d_ws;
    bf16*  xb  = (bf16*)(w);
    bf16*  wqb = (bf16*)(w + (size_t) 8 * 1024 * 1024);
    bf16*  wkb = (bf16*)(w + (size_t)10 * 1024 * 1024);
    bf16*  wvb = (bf16*)(w + (size_t)12 * 1024 * 1024);
    bf16*  P0  = (bf16*)(w);
    bf16*  P1  = (bf16*)(w + (size_t) 8 * 1024 * 1024);
    bf16*  qb  = (bf16*)(w + (size_t)16 * 1024 * 1024);
    bf16*  kb  = (bf16*)(w + (size_t)24 * 1024 * 1024);
    bf16*  vt  = (bf16*)(w + (size_t)32 * 1024 * 1024);
    float* l0  = (float*)(w + (size_t)40 * 1024 * 1024);
    float* l1  = (float*)(w + (size_t)40 * 1024 * 1024 + 256 * 1024);
    bf16*  ao  = (bf16*)(w + (size_t)16 * 1024 * 1024);   // alias qb (dead)
    bf16*  wob = (bf16*)(w + (size_t)46 * 1024 * 1024);

    dim3 blk(256);
    convert_kernel<<<dim3(8192), blk, 0, stream>>>(x, Wq, Wk, Wv, Wo,
                                                   xb, wqb, wkb, wvb, wob);
    gemm128_kernel<<<dim3(32, 8, 3), blk, 0, stream>>>(xb, wqb, wkb, wvb, pos,
                                                       qb, kb, vt);
    attn_kernel<<<dim3(512), blk, 0, stream>>>(qb, kb, vt,
                                               P0, P1, l0, l1);
    combine_kernel<<<dim3(2048), blk, 0, stream>>>(P0, P1, l0, l1, ao);
    gemm64_kernel<<<dim3(64, 16), blk, 0, stream>>>(ao, wob, out);
}

// Round 6
// 275.440 us; speedup vs baseline: 2.1371x; 1.7304x over previous
//
#include <hip/hip_runtime.h>

#define S    4096
#define DM   1024
#define H    16
#define DK   64

typedef __bf16 bf16;
typedef __bf16 bf16x8 __attribute__((ext_vector_type(8)));
typedef __bf16 bf16x4 __attribute__((ext_vector_type(4)));
typedef float  f32x4  __attribute__((ext_vector_type(4)));

// ---------------------------------------------------------------------------
// R6 QKV GEMM: C(4096x1024) = x @ W^T. EXACT R3 structure (64x64 tile, BK=64,
// 4 waves 2x2, reg-staged LDS stride 72) — proven counters: 68.6us, WRITE
// 26MB, FETCH 30MB, 0-ish conflicts. R4/R5's 128^2 + global_load_lds carried
// an unexplained 45x WRITE amplification (1.1+ GB at 3.5 TB/s) that survived
// an epilogue rewrite — structure abandoned (3rd failure of 128^2 on this op).
// NEW vs R3: reads x and W directly as FP32 and converts to bf16 in-register
// during staging (kernel is LDS-pipe-bound, VALU 32% -> casts ride free).
// This deletes the convert_kernel and one launch gap (~20us of R3's ~50us
// inter-kernel overhead).
//   z=0: Q -> fused RoPE, *0.125*log2(e), bf16 [h][s][d]
//   z=1: K -> fused RoPE,                 bf16 [h][s][d]
//   z=2: V ->                             bf16 [h][d][s] (transposed)
// ---------------------------------------------------------------------------
__global__ __launch_bounds__(256)
void gemmqkv_kernel(const float* __restrict__ A,
                    const float* __restrict__ w0, const float* __restrict__ w1,
                    const float* __restrict__ w2,
                    const int* __restrict__ pos,
                    bf16* __restrict__ o0, bf16* __restrict__ o1,
                    bf16* __restrict__ o2)
{
    const int mode = blockIdx.z;
    const float* W = (mode == 0) ? w0 : (mode == 1 ? w1 : w2);
    bf16* Out      = (mode == 0) ? o0 : (mode == 1 ? o1 : o2);

    __shared__ bf16 As[64 * 72];
    __shared__ bf16 Bs[64 * 72];

    const int tid  = threadIdx.x;
    const int lane = tid & 63;
    const int wv   = tid >> 6;
    const int quad = lane >> 4;
    const int col  = lane & 15;
    const int wm   = wv >> 1, wn = wv & 1;

    const int tileM = blockIdx.x * 64;
    const int tileN = blockIdx.y * 64;

    const int ldRow = tid >> 2;         // 0..63
    const int ldK   = (tid & 3) * 16;   // 0,16,32,48 (elements)

    f32x4 acc[2][2] = {};

    for (int kc = 0; kc < DM; kc += 64) {
        // fp32 loads (16 elems = 4 f32x4 each for A and W), convert in-reg
        const float* ap = &A[(size_t)(tileM + ldRow) * DM + kc + ldK];
        const float* bp = &W[(size_t)(tileN + ldRow) * DM + kc + ldK];
        f32x4 av[4], bv[4];
#pragma unroll
        for (int j = 0; j < 4; j++) { av[j] = ((const f32x4*)ap)[j]; }
#pragma unroll
        for (int j = 0; j < 4; j++) { bv[j] = ((const f32x4*)bp)[j]; }
        bf16x8 a0, a1, b0, b1;
#pragma unroll
        for (int r = 0; r < 4; r++) {
            a0[r]     = (bf16)av[0][r];  a0[r + 4] = (bf16)av[1][r];
            a1[r]     = (bf16)av[2][r];  a1[r + 4] = (bf16)av[3][r];
            b0[r]     = (bf16)bv[0][r];  b0[r + 4] = (bf16)bv[1][r];
            b1[r]     = (bf16)bv[2][r];  b1[r + 4] = (bf16)bv[3][r];
        }
        __syncthreads();                       // prior-iter LDS reads done
        *(bf16x8*)&As[ldRow * 72 + ldK]     = a0;
        *(bf16x8*)&As[ldRow * 72 + ldK + 8] = a1;
        *(bf16x8*)&Bs[ldRow * 72 + ldK]     = b0;
        *(bf16x8*)&Bs[ldRow * 72 + ldK + 8] = b1;
        __syncthreads();

        for (int kk = 0; kk < 2; kk++) {
            bf16x8 af0 = *(const bf16x8*)&As[(wm * 32 + 0 * 16 + col) * 72 + kk * 32 + quad * 8];
            bf16x8 af1 = *(const bf16x8*)&As[(wm * 32 + 1 * 16 + col) * 72 + kk * 32 + quad * 8];
            bf16x8 bf0 = *(const bf16x8*)&Bs[(wn * 32 + 0 * 16 + col) * 72 + kk * 32 + quad * 8];
            bf16x8 bf1 = *(const bf16x8*)&Bs[(wn * 32 + 1 * 16 + col) * 72 + kk * 32 + quad * 8];

            acc[0][0] = __builtin_amdgcn_mfma_f32_16x16x32_bf16(af0, bf0, acc[0][0], 0, 0, 0);
            acc[0][1] = __builtin_amdgcn_mfma_f32_16x16x32_bf16(af0, bf1, acc[0][1], 0, 0, 0);
            acc[1][0] = __builtin_amdgcn_mfma_f32_16x16x32_bf16(af1, bf0, acc[1][0], 0, 0, 0);
            acc[1][1] = __builtin_amdgcn_mfma_f32_16x16x32_bf16(af1, bf1, acc[1][1], 0, 0, 0);
        }
    }

    // Epilogue (R3-proven). C/D layout: col = lane&15, row = quad*4 + r
    for (int fm = 0; fm < 2; fm++)
    for (int fn = 0; fn < 2; fn++) {
        f32x4 v = acc[fm][fn];
        const int n = tileN + wn * 32 + fn * 16 + col;
        for (int r = 0; r < 4; r++) {
            const int m = tileM + wm * 32 + fm * 16 + quad * 4 + r;
            float val = v[r];
            if (mode <= 1) {
                // RoPE: pairs (2i,2i+1); partner value lives in lane^1
                float part = __shfl_xor(val, 1);
                const int d = n & 63;
                const int i = d >> 1;
                float inv = exp2f(-(float)i * 0.41524101186092034f); // 1e4^(-i/32)
                float ang = (float)pos[m] * inv;
                float c = cosf(ang), sn = sinf(ang);
                float rot = (n & 1) ? (val * c + part * sn)
                                    : (val * c - part * sn);
                // Q: fold 1/sqrt(DK) AND log2(e) so attn can use raw exp2
                if (mode == 0) rot *= 0.18033688011112042f;   // 0.125*log2(e)
                Out[((size_t)(n >> 6) * S + m) * 64 + d] = (bf16)rot;
            } else {
                Out[(size_t)n * S + m] = (bf16)val;           // V^T [h][d][s]
            }
        }
    }
}

// ---------------------------------------------------------------------------
// R6 out-projection: out(4096x1024 fp32) = ao @ Wo^T. R3-proven 64^2
// structure; A is bf16 (ao), Wo read directly as fp32 and converted in-reg.
// Coalesced fp32 epilogue (n-consecutive lanes -> 64B sectors).
// ---------------------------------------------------------------------------
__global__ __launch_bounds__(256)
void gemmo_kernel(const bf16* __restrict__ A,
                  const float* __restrict__ W,
                  float* __restrict__ of)
{
    __shared__ bf16 As[64 * 72];
    __shared__ bf16 Bs[64 * 72];

    const int tid  = threadIdx.x;
    const int lane = tid & 63;
    const int wv   = tid >> 6;
    const int quad = lane >> 4;
    const int col  = lane & 15;
    const int wm   = wv >> 1, wn = wv & 1;

    const int tileM = blockIdx.x * 64;
    const int tileN = blockIdx.y * 64;

    const int ldRow = tid >> 2;         // 0..63
    const int ldK   = (tid & 3) * 16;   // 0,16,32,48 (elements)

    f32x4 acc[2][2] = {};

    for (int kc = 0; kc < DM; kc += 64) {
        bf16x8 a0 = *(const bf16x8*)&A[(size_t)(tileM + ldRow) * DM + kc + ldK];
        bf16x8 a1 = *(const bf16x8*)&A[(size_t)(tileM + ldRow) * DM + kc + ldK + 8];
        const float* bp = &W[(size_t)(tileN + ldRow) * DM + kc + ldK];
        f32x4 bv[4];
#pragma unroll
        for (int j = 0; j < 4; j++) { bv[j] = ((const f32x4*)bp)[j]; }
        bf16x8 b0, b1;
#pragma unroll
        for (int r = 0; r < 4; r++) {
            b0[r]     = (bf16)bv[0][r];  b0[r + 4] = (bf16)bv[1][r];
            b1[r]     = (bf16)bv[2][r];  b1[r + 4] = (bf16)bv[3][r];
        }
        __syncthreads();                       // prior-iter LDS reads done
        *(bf16x8*)&As[ldRow * 72 + ldK]     = a0;
        *(bf16x8*)&As[ldRow * 72 + ldK + 8] = a1;
        *(bf16x8*)&Bs[ldRow * 72 + ldK]     = b0;
        *(bf16x8*)&Bs[ldRow * 72 + ldK + 8] = b1;
        __syncthreads();

        for (int kk = 0; kk < 2; kk++) {
            bf16x8 af0 = *(const bf16x8*)&As[(wm * 32 + 0 * 16 + col) * 72 + kk * 32 + quad * 8];
            bf16x8 af1 = *(const bf16x8*)&As[(wm * 32 + 1 * 16 + col) * 72 + kk * 32 + quad * 8];
            bf16x8 bf0 = *(const bf16x8*)&Bs[(wn * 32 + 0 * 16 + col) * 72 + kk * 32 + quad * 8];
            bf16x8 bf1 = *(const bf16x8*)&Bs[(wn * 32 + 1 * 16 + col) * 72 + kk * 32 + quad * 8];

            acc[0][0] = __builtin_amdgcn_mfma_f32_16x16x32_bf16(af0, bf0, acc[0][0], 0, 0, 0);
            acc[0][1] = __builtin_amdgcn_mfma_f32_16x16x32_bf16(af0, bf1, acc[0][1], 0, 0, 0);
            acc[1][0] = __builtin_amdgcn_mfma_f32_16x16x32_bf16(af1, bf0, acc[1][0], 0, 0, 0);
            acc[1][1] = __builtin_amdgcn_mfma_f32_16x16x32_bf16(af1, bf1, acc[1][1], 0, 0, 0);
        }
    }

    for (int fm = 0; fm < 2; fm++)
    for (int fn = 0; fn < 2; fn++) {
        f32x4 v = acc[fm][fn];
        const int n = tileN + wn * 32 + fn * 16 + col;
        for (int r = 0; r < 4; r++) {
            const int m = tileM + wm * 32 + fm * 16 + quad * 4 + r;
            of[(size_t)m * DM + n] = v[r];
        }
    }
}

// ---------------------------------------------------------------------------
// Flash attention (causal), transposed scores: St = K.Q^T, col = query.
// UNSHIFTED softmax -> partial (o,l) over disjoint key ranges sum linearly.
// R3 structure (verified): 64 queries/wave, split-K=2, antithetic pairing,
// XCD head-pinning. ~60us (below top-5 cutoff since R3).
// ---------------------------------------------------------------------------
__global__ __launch_bounds__(256, 2)
void attn_kernel(const bf16* __restrict__ q, const bf16* __restrict__ k,
                 const bf16* __restrict__ vt,
                 bf16* __restrict__ P0g, bf16* __restrict__ P1g,
                 float* __restrict__ l0g, float* __restrict__ l1g)
{
    const int bid = blockIdx.x;
    const int xcd = bid & 7;
    const int b3  = (bid >> 3) & 1;
    const int u   = (bid >> 4) & 15;
    const int b8  = (bid >> 8) & 1;
    const int h   = (xcd << 1) | b8;
    const int z   = b3;
    const int QB  = (b3 == b8) ? (15 - u) : u;   // antithetic pair balance

    const int tid  = threadIdx.x;
    const int lane = tid & 63;
    const int wv   = tid >> 6;
    const int quad = lane >> 4;
    const int col  = lane & 15;

    const int T2  = 2 * QB + 2;          // tiles per split-K chunk
    const int kt0 = z * T2;
    const int kt1 = kt0 + T2;

    __shared__ bf16 Ks[64 * 72];         // K[key][d],   padded (2-way free)
    __shared__ bf16 Vs[64 * 72];         // V^T[d][key], padded
    __shared__ bf16 plds[4][64 * 40];    // per-wave P half-tile [q][32key+pad]

    const int qbase = QB * 256 + wv * 64;    // wave owns 64 queries

    // Q as B-operand fragments: B[n=q][kdim=d], 4 q-groups of 16
    bf16x8 qf[4][2];
#pragma unroll
    for (int qt = 0; qt < 4; qt++) {
        const bf16* qr = &q[((size_t)(h * S + qbase + qt * 16 + col)) * 64];
        qf[qt][0] = *(const bf16x8*)(qr + quad * 8);
        qf[qt][1] = *(const bf16x8*)(qr + 32 + quad * 8);
    }

    float li[4] = {};
    f32x4 o[4][4] = {};                  // [dg][qt]

    const int srow = tid >> 2;
    const int sseg = (tid & 3) * 16;
    const bf16* kg_ = k  + ((size_t)h * S) * 64;
    const bf16* vg_ = vt + ((size_t)h * 64) * S;

    // preload first tile of this chunk
    bf16x8 kr0 = *(const bf16x8*)(kg_ + (size_t)(kt0 * 64 + srow) * 64 + sseg);
    bf16x8 kr1 = *(const bf16x8*)(kg_ + (size_t)(kt0 * 64 + srow) * 64 + sseg + 8);
    bf16x8 vr0 = *(const bf16x8*)(vg_ + (size_t)srow * S + kt0 * 64 + sseg);
    bf16x8 vr1 = *(const bf16x8*)(vg_ + (size_t)srow * S + kt0 * 64 + sseg + 8);

    for (int kt = kt0; kt < kt1; kt++) {
        const int kbase = kt * 64;

        __syncthreads();                 // prior-iter LDS fragment reads done
        *(bf16x8*)&Ks[srow * 72 + sseg]     = kr0;
        *(bf16x8*)&Ks[srow * 72 + sseg + 8] = kr1;
        *(bf16x8*)&Vs[srow * 72 + sseg]     = vr0;
        *(bf16x8*)&Vs[srow * 72 + sseg + 8] = vr1;
        __syncthreads();

        // register-prefetch next tile (overlaps with compute below)
        if (kt + 1 < kt1) {
            const int nb = kbase + 64;
            kr0 = *(const bf16x8*)(kg_ + (size_t)(nb + srow) * 64 + sseg);
            kr1 = *(const bf16x8*)(kg_ + (size_t)(nb + srow) * 64 + sseg + 8);
            vr0 = *(const bf16x8*)(vg_ + (size_t)srow * S + nb + sseg);
            vr1 = *(const bf16x8*)(vg_ + (size_t)srow * S + nb + sseg + 8);
        }

        const bool diag = (kt >= (QB << 2));   // tile overlaps causal diagonal

        // Process 64 keys in two 32-key halves (plds holds one half)
#pragma unroll
        for (int half = 0; half < 2; half++) {
            __builtin_amdgcn_wave_barrier();   // prior half's P reads done
#pragma unroll
            for (int kg2 = 0; kg2 < 2; kg2++) {
                const int kg = half * 2 + kg2;
                // K A-fragments (shared across the 4 q-groups)
                bf16x8 kf0 = *(const bf16x8*)&Ks[(kg * 16 + col) * 72 + quad * 8];
                bf16x8 kf1 = *(const bf16x8*)&Ks[(kg * 16 + col) * 72 + 32 + quad * 8];

                f32x4 st[4];
                __builtin_amdgcn_s_setprio(1);
#pragma unroll
                for (int qt = 0; qt < 4; qt++) {
                    f32x4 zz = {};
                    zz = __builtin_amdgcn_mfma_f32_16x16x32_bf16(kf0, qf[qt][0], zz, 0, 0, 0);
                    zz = __builtin_amdgcn_mfma_f32_16x16x32_bf16(kf1, qf[qt][1], zz, 0, 0, 0);
                    st[qt] = zz;
                }
                __builtin_amdgcn_s_setprio(0);

                if (diag) {
#pragma unroll
                    for (int qt = 0; qt < 4; qt++) {
                        const int gq = qbase + qt * 16 + col;
#pragma unroll
                        for (int r = 0; r < 4; r++) {
                            const int gk = kbase + kg * 16 + quad * 4 + r;
                            st[qt][r] = (gk > gq) ? -1e30f : st[qt][r];
                        }
                    }
                }

                // p = exp2(s) raw; accumulate per-lane partial l (reduce once
                // at the end); write P half-tile (b64, packed)
#pragma unroll
                for (int qt = 0; qt < 4; qt++) {
                    bf16x4 pk;
#pragma unroll
                    for (int r = 0; r < 4; r++) {
                        float p;
                        asm("v_exp_f32 %0, %1" : "=v"(p) : "v"(st[qt][r]));
                        li[qt] += p;
                        pk[r] = (bf16)p;
                    }
                    *(bf16x4*)&plds[wv][(qt * 16 + col) * 40 + kg2 * 16 + quad * 4] = pk;
                }
            }

            __builtin_amdgcn_wave_barrier();   // P writes before P reads

            // PV for this 32-key half: O^T[d][q] += V^T[d][key] * P^T[key][q]
            bf16x8 pb[4];
#pragma unroll
            for (int qt = 0; qt < 4; qt++)
                pb[qt] = *(const bf16x8*)&plds[wv][(qt * 16 + col) * 40 + quad * 8];

            __builtin_amdgcn_s_setprio(1);
#pragma unroll
            for (int dg = 0; dg < 4; dg++) {
                bf16x8 va = *(const bf16x8*)&Vs[(dg * 16 + col) * 72 + half * 32 + quad * 8];
#pragma unroll
                for (int qt = 0; qt < 4; qt++)
                    o[dg][qt] = __builtin_amdgcn_mfma_f32_16x16x32_bf16(va, pb[qt], o[dg][qt], 0, 0, 0);
            }
            __builtin_amdgcn_s_setprio(0);
        }
    }

    // Cross-quad l reduction (keys split across quads), once per kernel
#pragma unroll
    for (int qt = 0; qt < 4; qt++) {
        li[qt] += __shfl_xor(li[qt], 16);
        li[qt] += __shfl_xor(li[qt], 32);
    }

    // Epilogue: store UNNORMALIZED partial o (bf16) + partial l (fp32).
    bf16*  Pz = z ? P1g : P0g;
    float* lz = z ? l1g : l0g;
#pragma unroll
    for (int dg = 0; dg < 4; dg++)
#pragma unroll
    for (int qt = 0; qt < 4; qt++) {
        const int gq = qbase + qt * 16 + col;
        bf16x4 ov;
#pragma unroll
        for (int r = 0; r < 4; r++) ov[r] = (bf16)o[dg][qt][r];
        *(bf16x4*)&Pz[(size_t)gq * DM + h * 64 + dg * 16 + quad * 4] = ov;
    }
    if (quad == 0) {
#pragma unroll
        for (int qt = 0; qt < 4; qt++)
            lz[(size_t)h * S + qbase + qt * 16 + col] = li[qt];
    }
}

// ---------------------------------------------------------------------------
// Combine split-K partials: ao[s][dm] = (P0 + P1) / (l0[h][s] + l1[h][s]).
// ---------------------------------------------------------------------------
__global__ __launch_bounds__(256)
void combine_kernel(const bf16* __restrict__ P0, const bf16* __restrict__ P1,
                    const float* __restrict__ l0, const float* __restrict__ l1,
                    bf16* __restrict__ ao)
{
    const size_t i    = (size_t)blockIdx.x * 256 + threadIdx.x;  // 8-elem group
    const size_t base = i * 8;
    const int s  = (int)(base >> 10);          // DM = 1024
    const int dm = (int)(base & 1023);
    const int h  = dm >> 6;
    const float rli = 1.f / (l0[(size_t)h * S + s] + l1[(size_t)h * S + s]);
    bf16x8 a = *(const bf16x8*)&P0[base];
    bf16x8 b = *(const bf16x8*)&P1[base];
    bf16x8 ov;
    for (int r = 0; r < 8; r++)
        ov[r] = (bf16)(((float)a[r] + (float)b[r]) * rli);
    *(bf16x8*)&ao[base] = ov;
}

// ---------------------------------------------------------------------------
extern "C" void kernel_launch(void* const* d_in, const int* in_sizes, int n_in,
                              void* d_out, int out_size, void* d_ws, size_t ws_size,
                              hipStream_t stream)
{
    const float* x   = (const float*)d_in[0];
    const int*   pos = (const int*)d_in[1];
    const float* Wq  = (const float*)d_in[2];
    const float* Wk  = (const float*)d_in[3];
    const float* Wv  = (const float*)d_in[4];
    const float* Wo  = (const float*)d_in[5];
    float* out = (float*)d_out;   // reference output dtype is float32

    // workspace layout (48 MB):
    //   [0, 8M)    P0 bf16 partial
    //   [8,16M)    P1 bf16 partial
    //   [16,24M)   qb  bf16 [h][s][d]   -> ao bf16 [s][DM] (after attn)
    //   [24,32M)   kb  bf16 [h][s][d]
    //   [32,40M)   vt  bf16 [h][d][s]
    //   [40,40.25M) l0 fp32 [h][s]   [40.25,40.5M) l1 fp32 [h][s]
    char* w = (char*)d_ws;
    bf16*  P0  = (bf16*)(w);
    bf16*  P1  = (bf16*)(w + (size_t) 8 * 1024 * 1024);
    bf16*  qb  = (bf16*)(w + (size_t)16 * 1024 * 1024);
    bf16*  kb  = (bf16*)(w + (size_t)24 * 1024 * 1024);
    bf16*  vt  = (bf16*)(w + (size_t)32 * 1024 * 1024);
    float* l0  = (float*)(w + (size_t)40 * 1024 * 1024);
    float* l1  = (float*)(w + (size_t)40 * 1024 * 1024 + 256 * 1024);
    bf16*  ao  = (bf16*)(w + (size_t)16 * 1024 * 1024);   // alias qb (dead)

    dim3 blk(256);
    gemmqkv_kernel<<<dim3(64, 16, 3), blk, 0, stream>>>(x, Wq, Wk, Wv, pos,
                                                        qb, kb, vt);
    attn_kernel<<<dim3(512), blk, 0, stream>>>(qb, kb, vt,
                                               P0, P1, l0, l1);
    combine_kernel<<<dim3(2048), blk, 0, stream>>>(P0, P1, l0, l1, ao);
    gemmo_kernel<<<dim3(64, 16), blk, 0, stream>>>(ao, Wo, out);
}